// Round 7
// baseline (674.618 us; speedup 1.0000x reference)
//
#include <hip/hip_runtime.h>

// Problem constants (reference: N=100000, E=1600000, IN=128, OUT=256)
#define NODES 100000
#define EDGES 1600000
#define FIN   128
#define FOUT  256
#define NBUCK 196   // ceil(NODES/512), bucket = dst >> 9

typedef __bf16 bf16;
typedef __bf16 bf16x8 __attribute__((ext_vector_type(8)));
typedef __bf16 bf16x4 __attribute__((ext_vector_type(4)));
typedef float  f32x4  __attribute__((ext_vector_type(4)));

// ---------------- dtype detection ----------------
// flags[0] = 1 if float tensors are bf16, 0 if float32
// flags[1] = 1 if edge_index is int64, 0 if int32
__global__ __launch_bounds__(256) void detect_kernel(const void* __restrict__ x,
                                                     const int* __restrict__ ei,
                                                     int* __restrict__ flags) {
    __shared__ int s_f32_evidence;
    __shared__ int s_odd_nonzero;
    int t = threadIdx.x;
    if (t == 0) { s_f32_evidence = 0; s_odd_nonzero = 0; }
    __syncthreads();
    const bf16* xb = (const bf16*)x;
    int local_f32 = 0;
    for (int i = t; i < 4096; i += 256) {
        float v = fabsf((float)xb[i]);
        if (!(v < 1e4f)) local_f32 = 1;   // huge / inf / NaN -> data is f32
    }
    if (local_f32) atomicOr(&s_f32_evidence, 1);
    int local_odd = 0;
    for (int k = t; k < 1024; k += 256) {
        if (ei[2 * k + 1] != 0) local_odd = 1;   // nonzero odd word -> int32 data
    }
    if (local_odd) atomicOr(&s_odd_nonzero, 1);
    __syncthreads();
    if (t == 0) {
        flags[0] = s_f32_evidence ? 0 : 1;
        flags[1] = s_odd_nonzero ? 0 : 1;
    }
}

__device__ __forceinline__ int edge_at(const int* __restrict__ ei, int which, int i,
                                       int is64) {
    if (is64) return ei[2 * (which * EDGES + i)];   // little-endian low word
    return ei[which * EDGES + i];
}

// ---------------- degree count + bucket histogram ----------------
__global__ __launch_bounds__(512) void deg_count(const int* __restrict__ ei,
                                                 int* __restrict__ deg,
                                                 int* __restrict__ bhist,
                                                 const int* __restrict__ flags) {
    __shared__ int lh[256];
    int t = threadIdx.x;
    if (t < 256) lh[t] = 0;
    __syncthreads();
    int i = blockIdx.x * 512 + t;
    if (i < EDGES) {
        int is64 = flags[1];
        int s = edge_at(ei, 0, i, is64);
        int d = edge_at(ei, 1, i, is64);
        if (s >= 0 && s < NODES && d >= 0 && d < NODES) {
            atomicAdd(&deg[d], 1);
            atomicAdd(&lh[d >> 9], 1);
        }
    }
    __syncthreads();
    if (t < NBUCK && lh[t] > 0) atomicAdd(&bhist[t], lh[t]);
}

// ---------------- exclusive scan for col_ptr (+ fused dinv) ----------------
__global__ __launch_bounds__(1024) void scan1(const int* __restrict__ deg,
                                              int* __restrict__ col_ptr,
                                              int* __restrict__ blksum,
                                              float* __restrict__ dinv, int n) {
    __shared__ int sm[1024];
    int t = threadIdx.x;
    int i = blockIdx.x * 1024 + t;
    int v = (i < n) ? deg[i] : 0;
    if (i < n) dinv[i] = rsqrtf((float)v + 1.0f);   // +1 = self-loop
    sm[t] = v;
    __syncthreads();
    for (int off = 1; off < 1024; off <<= 1) {
        int u = (t >= off) ? sm[t - off] : 0;
        __syncthreads();
        sm[t] += u;
        __syncthreads();
    }
    if (i <= n) col_ptr[i] = sm[t] - v;
    if (t == 1023) blksum[blockIdx.x] = sm[t];
}

// block 0: exclusive scan of blk[nblk]; block 1: bhist -> bbase/bcur
__global__ __launch_bounds__(256) void scan_small(int* __restrict__ blk, int nblk,
                                                  const int* __restrict__ bhist,
                                                  int* __restrict__ bbase,
                                                  int* __restrict__ bcur) {
    __shared__ int sm[256];
    int t = threadIdx.x;
    if (blockIdx.x == 0) {
        int v = (t < nblk) ? blk[t] : 0;
        sm[t] = v;
        __syncthreads();
        for (int off = 1; off < 256; off <<= 1) {
            int u = (t >= off) ? sm[t - off] : 0;
            __syncthreads();
            sm[t] += u;
            __syncthreads();
        }
        if (t < nblk) blk[t] = sm[t] - v;
    } else {
        int v = (t < NBUCK) ? bhist[t] : 0;
        sm[t] = v;
        __syncthreads();
        for (int off = 1; off < 256; off <<= 1) {
            int u = (t >= off) ? sm[t - off] : 0;
            __syncthreads();
            sm[t] += u;
            __syncthreads();
        }
        if (t < NBUCK) {
            int ex = sm[t] - v;
            bbase[t] = ex;
            bcur[t]  = ex;
            if (t == NBUCK - 1) bbase[NBUCK] = sm[t];
        }
    }
}

__global__ __launch_bounds__(256) void scan3(int* __restrict__ col_ptr,
                                             const int* __restrict__ blkoff, int n) {
    int i = blockIdx.x * 256 + threadIdx.x;
    if (i <= n) col_ptr[i] += blkoff[i >> 10];
}

// ---------------- partition: bucket-group edges via LDS staging ----------------
#define EPB 4096
__global__ __launch_bounds__(256) void partition_edges(const int* __restrict__ ei,
                                                       int* __restrict__ bcur,
                                                       uint2* __restrict__ pairs,
                                                       const int* __restrict__ flags) {
    __shared__ int lh[256], sc[256], lst[256], lcu[256], gb[256];
    __shared__ uint2 stage[EPB];
    int t = threadIdx.x;
    int base = blockIdx.x * EPB;
    int is64 = flags[1];

    lh[t] = 0;
    __syncthreads();

    int es[16], ed[16];
#pragma unroll
    for (int j = 0; j < 16; ++j) {
        int i = base + j * 256 + t;
        int s = -1, d = -1;
        if (i < EDGES) {
            s = edge_at(ei, 0, i, is64);
            d = edge_at(ei, 1, i, is64);
            if (s < 0 || s >= NODES || d < 0 || d >= NODES) d = -1;
        }
        es[j] = s; ed[j] = d;
        if (d >= 0) atomicAdd(&lh[d >> 9], 1);
    }
    __syncthreads();
    sc[t] = lh[t];
    __syncthreads();
    for (int off = 1; off < 256; off <<= 1) {
        int u = (t >= off) ? sc[t - off] : 0;
        __syncthreads();
        sc[t] += u;
        __syncthreads();
    }
    int start = sc[t] - lh[t];
    lst[t] = start;
    lcu[t] = start;
    __syncthreads();
#pragma unroll
    for (int j = 0; j < 16; ++j) {
        if (ed[j] >= 0) {
            int p = atomicAdd(&lcu[ed[j] >> 9], 1);
            stage[p] = make_uint2((unsigned)es[j], (unsigned)ed[j]);
        }
    }
    __syncthreads();
    if (t < NBUCK && lh[t] > 0) gb[t] = atomicAdd(&bcur[t], lh[t]);
    __syncthreads();
    int nval = sc[255];
    for (int slot = t; slot < nval; slot += 256) {
        uint2 e = stage[slot];
        int b = (int)(e.y >> 9);
        pairs[(size_t)gb[b] + (slot - lst[b])] = e;
    }
}

// ---------------- fine fill: per-bucket scatter, L2-resident window ----------------
__global__ __launch_bounds__(512) void fine_fill(const uint2* __restrict__ pairs,
                                                 const int* __restrict__ bbase,
                                                 const int* __restrict__ col_ptr,
                                                 int* __restrict__ col_idx) {
    __shared__ int lcur[512];
    int b = blockIdx.x;
    int t = threadIdx.x;
    int node = (b << 9) + t;
    lcur[t] = (node < NODES) ? col_ptr[node] : 0;
    __syncthreads();
    int beg = bbase[b], end = bbase[b + 1];
    for (int i = beg + t; i < end; i += 512) {
        uint2 e = pairs[i];
        int pos = atomicAdd(&lcur[e.y & 511], 1);
        col_idx[pos] = (int)e.x;
    }
}

// ---------------- pack all weights (MFMA B-frag order) + biases ----------------
__global__ __launch_bounds__(256) void pack_all(const void* __restrict__ W1,
                                                const void* __restrict__ W2,
                                                const void* __restrict__ Wp,
                                                const void* __restrict__ b1,
                                                const void* __restrict__ b2,
                                                const void* __restrict__ bp,
                                                bf16* __restrict__ W1p, bf16* __restrict__ W2p,
                                                bf16* __restrict__ Wpp, bf16* __restrict__ b1b,
                                                bf16* __restrict__ b2b, bf16* __restrict__ bpb,
                                                const int* __restrict__ flags) {
    int fl = flags[0];
    int b = blockIdx.x;
    if (b < 512) {
        const void* W; bf16* Wo; int idx;
        if (b < 128)      { W = W1; Wo = W1p; idx = b * 256 + threadIdx.x; }
        else if (b < 384) { W = W2; Wo = W2p; idx = (b - 128) * 256 + threadIdx.x; }
        else              { W = Wp; Wo = Wpp; idx = (b - 384) * 256 + threadIdx.x; }
        int j    = idx & 7;
        int lane = (idx >> 3) & 63;
        int ct   = (idx >> 9) & 15;
        int kt   = idx >> 13;
        int k = kt * 32 + (lane >> 4) * 8 + j;
        int n = ct * 16 + (lane & 15);
        Wo[idx] = fl ? ((const bf16*)W)[k * 256 + n]
                     : (bf16)(((const float*)W)[k * 256 + n]);
    } else {
        const void* bb; bf16* bo;
        if (b == 512)      { bb = b1; bo = b1b; }
        else if (b == 513) { bb = b2; bo = b2b; }
        else               { bb = bp; bo = bpb; }
        int i = threadIdx.x;
        bo[i] = fl ? ((const bf16*)bb)[i] : (bf16)(((const float*)bb)[i]);
    }
}

// ---------------- proj GEMM (K=128) + emit Xs = dinv*x (bf16) ----------------
__global__ __launch_bounds__(256) void gemm_proj(const void* __restrict__ Av,
                                                 const bf16* __restrict__ Wpk,
                                                 const float* __restrict__ dinv,
                                                 const bf16* __restrict__ bias,
                                                 void* __restrict__ outv,
                                                 bf16* __restrict__ Xs,
                                                 const int* __restrict__ flags) {
    int a_f32 = (flags[0] == 0);
    int wave = threadIdx.x >> 6;
    int lane = threadIdx.x & 63;
    int row0 = blockIdx.x * 64;
    int lr = lane & 15;
    int lk = (lane >> 4) * 8;

    int arow[4];
    float di4[4];
#pragma unroll
    for (int rf = 0; rf < 4; ++rf) {
        int r = row0 + rf * 16 + lr;
        arow[rf] = r < NODES ? r : (NODES - 1);
        di4[rf] = dinv[arow[rf]];
    }

    f32x4 acc[4][4];
    f32x4 z = {0.f, 0.f, 0.f, 0.f};
#pragma unroll
    for (int i = 0; i < 4; ++i)
#pragma unroll
        for (int j = 0; j < 4; ++j) acc[i][j] = z;

    for (int kt = 0; kt < 4; ++kt) {
        bf16x8 af[4];
        if (!a_f32) {
            const bf16* Ab = (const bf16*)Av + kt * 32 + lk;
#pragma unroll
            for (int rf = 0; rf < 4; ++rf)
                af[rf] = *(const bf16x8*)(Ab + (size_t)arow[rf] * FIN);
        } else {
            const float* Af = (const float*)Av + kt * 32 + lk;
#pragma unroll
            for (int rf = 0; rf < 4; ++rf) {
                const float* p = Af + (size_t)arow[rf] * FIN;
                f32x4 lo = *(const f32x4*)p;
                f32x4 hi = *(const f32x4*)(p + 4);
                af[rf][0] = (bf16)lo[0]; af[rf][1] = (bf16)lo[1];
                af[rf][2] = (bf16)lo[2]; af[rf][3] = (bf16)lo[3];
                af[rf][4] = (bf16)hi[0]; af[rf][5] = (bf16)hi[1];
                af[rf][6] = (bf16)hi[2]; af[rf][7] = (bf16)hi[3];
            }
        }
#pragma unroll
        for (int rf = 0; rf < 4; ++rf) {
            bf16x8 xsv;
#pragma unroll
            for (int j = 0; j < 8; ++j) xsv[j] = (bf16)(di4[rf] * (float)af[rf][j]);
            *(bf16x8*)(Xs + (size_t)arow[rf] * FIN + kt * 32 + lk) = xsv;
        }
        const bf16* wb = Wpk + ((size_t)(kt * 16 + wave * 4) * 64 + lane) * 8;
        bf16x8 bfv[4];
#pragma unroll
        for (int cf = 0; cf < 4; ++cf)
            bfv[cf] = *(const bf16x8*)(wb + cf * 512);
#pragma unroll
        for (int rf = 0; rf < 4; ++rf)
#pragma unroll
            for (int cf = 0; cf < 4; ++cf)
                acc[rf][cf] = __builtin_amdgcn_mfma_f32_16x16x32_bf16(
                    af[rf], bfv[cf], acc[rf][cf], 0, 0, 0);
    }

    int rb = (lane >> 4) * 4;
    int out_f32 = a_f32;
#pragma unroll
    for (int rf = 0; rf < 4; ++rf) {
#pragma unroll
        for (int r = 0; r < 4; ++r) {
            int row = row0 + rf * 16 + rb + r;
            if (row >= NODES) continue;
#pragma unroll
            for (int cf = 0; cf < 4; ++cf) {
                int col = wave * 64 + cf * 16 + lr;
                float v = acc[rf][cf][r] + (float)bias[col];
                size_t off = (size_t)row * 256 + col;
                if (out_f32) __builtin_nontemporal_store(v, (float*)outv + off);
                else         ((bf16*)outv)[off]  = (bf16)v;
            }
        }
    }
}

// ---------------- GEMM tile (bf16 A): 64 rows x 256 cols / block ----------------
__global__ __launch_bounds__(256) void gemm_tile(const bf16* __restrict__ A,
                                                 const bf16* __restrict__ Wpk,
                                                 int K,
                                                 const float* __restrict__ dinv,
                                                 const bf16* __restrict__ bias,
                                                 int relu,
                                                 bf16* __restrict__ out) {
    int wave = threadIdx.x >> 6;
    int lane = threadIdx.x & 63;
    int row0 = blockIdx.x * 64;
    int lr = lane & 15;
    int lk = (lane >> 4) * 8;

    int arow[4];
#pragma unroll
    for (int rf = 0; rf < 4; ++rf) {
        int r = row0 + rf * 16 + lr;
        arow[rf] = r < NODES ? r : (NODES - 1);
    }

    f32x4 acc[4][4];
    f32x4 z = {0.f, 0.f, 0.f, 0.f};
#pragma unroll
    for (int i = 0; i < 4; ++i)
#pragma unroll
        for (int j = 0; j < 4; ++j) acc[i][j] = z;

    int ktiles = K >> 5;
    for (int kt = 0; kt < ktiles; ++kt) {
        const bf16* Ab = A + kt * 32 + lk;
        bf16x8 af[4];
#pragma unroll
        for (int rf = 0; rf < 4; ++rf)
            af[rf] = *(const bf16x8*)(Ab + (size_t)arow[rf] * K);
        const bf16* wb = Wpk + ((size_t)(kt * 16 + wave * 4) * 64 + lane) * 8;
        bf16x8 bfv[4];
#pragma unroll
        for (int cf = 0; cf < 4; ++cf)
            bfv[cf] = *(const bf16x8*)(wb + cf * 512);
#pragma unroll
        for (int rf = 0; rf < 4; ++rf)
#pragma unroll
            for (int cf = 0; cf < 4; ++cf)
                acc[rf][cf] = __builtin_amdgcn_mfma_f32_16x16x32_bf16(
                    af[rf], bfv[cf], acc[rf][cf], 0, 0, 0);
    }

    int rb = (lane >> 4) * 4;
#pragma unroll
    for (int rf = 0; rf < 4; ++rf) {
#pragma unroll
        for (int r = 0; r < 4; ++r) {
            int row = row0 + rf * 16 + rb + r;
            if (row >= NODES) continue;
            float s = dinv ? dinv[row] : 1.0f;
#pragma unroll
            for (int cf = 0; cf < 4; ++cf) {
                int col = wave * 64 + cf * 16 + lr;
                float v = acc[rf][cf][r] * s;
                if (bias) v += (float)bias[col];
                if (relu) v = fmaxf(v, 0.0f);
                out[(size_t)row * 256 + col] = (bf16)v;
            }
        }
    }
}

// ---------------- gather1: 128-f rows (256 B), 16 B/lane, 4 rows per load ----------------
// aggX[n] = dinv[n] * (sum_{s in N(n)} Xs[s] + Xs[n])
__global__ __launch_bounds__(256) void gather1(const int* __restrict__ col_ptr,
                                               const int* __restrict__ col_idx,
                                               const bf16* __restrict__ Xs,
                                               const float* __restrict__ dinv,
                                               bf16* __restrict__ aggX) {
    int wid  = (int)((blockIdx.x * 256 + threadIdx.x) >> 6);
    int lane = threadIdx.x & 63;
    if (wid >= NODES) return;
    int q  = lane >> 4;        // quarter: which of 4 rows per load
    int li = lane & 15;
    int c8 = li * 8;           // 8 feats = 16 B
    int beg = col_ptr[wid], end = col_ptr[wid + 1];

    float acc[8] = {0.f, 0.f, 0.f, 0.f, 0.f, 0.f, 0.f, 0.f};
    for (int chunk = beg; chunk < end; chunk += 64) {
        int cnt = end - chunk;
        if (cnt > 64) cnt = 64;
        int myidx = (lane < cnt) ? col_idx[chunk + lane] : 0;
        int j = 0;
        for (; j + 16 <= cnt; j += 16) {     // 4 loads, 16 edges in flight
            bf16x8 v[4];
#pragma unroll
            for (int l = 0; l < 4; ++l) {
                int s = __shfl(myidx, j + 4 * l + q);
                v[l] = *(const bf16x8*)(Xs + (size_t)s * FIN + c8);
            }
#pragma unroll
            for (int l = 0; l < 4; ++l)
#pragma unroll
                for (int k = 0; k < 8; ++k) acc[k] += (float)v[l][k];
        }
        for (; j < cnt; j += 4) {            // masked remainder
            if (j + q < cnt) {
                int s = __shfl(myidx, j + q);
                bf16x8 v = *(const bf16x8*)(Xs + (size_t)s * FIN + c8);
#pragma unroll
                for (int k = 0; k < 8; ++k) acc[k] += (float)v[k];
            }
        }
    }
    // fold the 4 quarters: lanes li, li+16, li+32, li+48 hold same feats
#pragma unroll
    for (int k = 0; k < 8; ++k) {
        acc[k] += __shfl_xor(acc[k], 16);
        acc[k] += __shfl_xor(acc[k], 32);
    }
    if (q == 0) {
        bf16x8 self = *(const bf16x8*)(Xs + (size_t)wid * FIN + c8);
        float di = dinv[wid];
        bf16x8 o;
#pragma unroll
        for (int k = 0; k < 8; ++k) o[k] = (bf16)(di * (acc[k] + (float)self[k]));
        *(bf16x8*)(aggX + (size_t)wid * FIN + c8) = o;
    }
}

// ---------------- gather2: 256-f rows (512 B), 16 B/lane, 2 rows per load ----------------
// out[n] = relu(dinv[n]*(sum Y2[s] + Y2[n]) + b2 + proj[n])
__global__ __launch_bounds__(256) void gather2(const int* __restrict__ col_ptr,
                                               const int* __restrict__ col_idx,
                                               const bf16* __restrict__ Y2,
                                               const float* __restrict__ dinv,
                                               const bf16* __restrict__ bias,
                                               const void* __restrict__ proj,
                                               void* __restrict__ outv,
                                               const int* __restrict__ flags) {
    int io_f32 = (flags[0] == 0);
    int wid  = (int)((blockIdx.x * 256 + threadIdx.x) >> 6);
    int lane = threadIdx.x & 63;
    if (wid >= NODES) return;
    int half = lane >> 5;      // which of 2 rows per load
    int li   = lane & 31;
    int c8   = li * 8;         // 8 feats = 16 B
    int beg = col_ptr[wid], end = col_ptr[wid + 1];

    float acc[8] = {0.f, 0.f, 0.f, 0.f, 0.f, 0.f, 0.f, 0.f};
    for (int chunk = beg; chunk < end; chunk += 64) {
        int cnt = end - chunk;
        if (cnt > 64) cnt = 64;
        int myidx = (lane < cnt) ? col_idx[chunk + lane] : 0;
        int j = 0;
        for (; j + 16 <= cnt; j += 16) {     // 8 loads, 16 edges in flight
            bf16x8 v[8];
#pragma unroll
            for (int l = 0; l < 8; ++l) {
                int s = __shfl(myidx, j + 2 * l + half);
                v[l] = *(const bf16x8*)(Y2 + (size_t)s * 256 + c8);
            }
#pragma unroll
            for (int l = 0; l < 8; ++l)
#pragma unroll
                for (int k = 0; k < 8; ++k) acc[k] += (float)v[l][k];
        }
        for (; j < cnt; j += 2) {            // masked remainder
            if (j + half < cnt) {
                int s = __shfl(myidx, j + half);
                bf16x8 v = *(const bf16x8*)(Y2 + (size_t)s * 256 + c8);
#pragma unroll
                for (int k = 0; k < 8; ++k) acc[k] += (float)v[k];
            }
        }
    }
    // fold halves: lanes li and li+32 hold same feats
#pragma unroll
    for (int k = 0; k < 8; ++k) acc[k] += __shfl_xor(acc[k], 32);

    if (half == 0) {
        bf16x8 selfv = *(const bf16x8*)(Y2 + (size_t)wid * 256 + c8);
        float di = dinv[wid];
        size_t base = (size_t)wid * 256 + c8;
        float res[8];
#pragma unroll
        for (int k = 0; k < 8; ++k)
            res[k] = di * (acc[k] + (float)selfv[k]) + (float)bias[c8 + k];
        if (io_f32) {
            const float* pp = (const float*)proj + base;
            f32x4 p0 = __builtin_nontemporal_load((const f32x4*)pp);
            f32x4 p1 = __builtin_nontemporal_load((const f32x4*)(pp + 4));
            f32x4 o0, o1;
#pragma unroll
            for (int k = 0; k < 4; ++k) {
                o0[k] = fmaxf(res[k] + p0[k], 0.0f);
                o1[k] = fmaxf(res[k + 4] + p1[k], 0.0f);
            }
            float* op = (float*)outv + base;
            __builtin_nontemporal_store(o0, (f32x4*)op);
            __builtin_nontemporal_store(o1, (f32x4*)(op + 4));
        } else {
            bf16x8 pv = *(const bf16x8*)((const bf16*)proj + base);
            bf16x8 o;
#pragma unroll
            for (int k = 0; k < 8; ++k)
                o[k] = (bf16)fmaxf(res[k] + (float)pv[k], 0.0f);
            *(bf16x8*)((bf16*)outv + base) = o;
        }
    }
}

__global__ __launch_bounds__(256) void zero_out(bf16* out, int nelem) {
    int i = blockIdx.x * 256 + threadIdx.x;
    if (i < nelem) out[i] = (bf16)0.0f;
}

extern "C" void kernel_launch(void* const* d_in, const int* in_sizes, int n_in,
                              void* d_out, int out_size, void* d_ws, size_t ws_size,
                              hipStream_t stream) {
    const void* x   = d_in[0];
    const int*  ei  = (const int*)d_in[1];
    const void* W1  = d_in[2];
    const void* b1  = d_in[3];
    const void* W2  = d_in[4];
    const void* b2  = d_in[5];
    const void* Wp  = d_in[6];
    const void* bp  = d_in[7];

    const size_t NEEDED = 401408ull * 3 + 1024ull * 4 + 6400000 + 65536 + 131072 + 65536
                        + 1536 + 25600000ull * 2 + 51200000ull;  // ~110.3 MB (known fit)
    if (ws_size < NEEDED) {
        zero_out<<<(NODES * 256 + 255) / 256, 256, 0, stream>>>((bf16*)d_out, NODES * 256);
        return;
    }
    char* w = (char*)d_ws;
    int*   col_ptr = (int*)w;   w += 401408;     // N+1 ints
    int*   deg     = (int*)w;   w += 401408;     // degree (memset with bhist)
    int*   bhist   = (int*)w;   w += 1024;       // 196 ints (contiguous after deg)
    float* dinv    = (float*)w; w += 401408;
    int*   blk     = (int*)w;   w += 1024;
    int*   flags   = (int*)w;   w += 1024;
    int*   bbase   = (int*)w;   w += 1024;       // 197 ints
    int*   bcur    = (int*)w;   w += 1024;
    int*   col_idx = (int*)w;   w += 6400000;    // E ints
    bf16*  W1p     = (bf16*)w;  w += 65536;
    bf16*  W2p     = (bf16*)w;  w += 131072;
    bf16*  Wpp     = (bf16*)w;  w += 65536;
    bf16*  b1b     = (bf16*)w;  w += 512;
    bf16*  b2b     = (bf16*)w;  w += 512;
    bf16*  bpb     = (bf16*)w;  w += 512;
    bf16*  Xs      = (bf16*)w;  w += 25600000;   // dinv*x (N x 128); pairs overlaid pre-GEMM
    bf16*  aggX    = (bf16*)w;  w += 25600000;   // S*x (N x 128)
    bf16*  H1      = (bf16*)w;  w += 51200000;   // relu(conv1) (N x 256)
    uint2* pairs   = (uint2*)Xs;                 // E pairs (12.8 MB), dead before Xs written
    bf16*  Y2      = Xs;                         // dinv*(H1@W2) overlays Xs+aggX (51.2 MB)

    const int NBLK = (NODES + 1 + 1023) / 1024;  // 98

    // 0) detect dtypes
    detect_kernel<<<1, 256, 0, stream>>>(x, ei, flags);

    // 1) degree + bucket histogram
    hipMemsetAsync(deg, 0, 401408 + 1024, stream);
    deg_count<<<(EDGES + 511) / 512, 512, 0, stream>>>(ei, deg, bhist, flags);

    // 2) scans (col_ptr + dinv fused; blk & bucket merged)
    scan1<<<NBLK, 1024, 0, stream>>>(deg, col_ptr, blk, dinv, NODES);
    scan_small<<<2, 256, 0, stream>>>(blk, NBLK, bhist, bbase, bcur);
    scan3<<<(NODES + 256) / 256, 256, 0, stream>>>(col_ptr, blk, NODES);

    // 3) CSR build: LDS-binned partition + per-bucket fine fill (write-amp ~1x)
    partition_edges<<<(EDGES + EPB - 1) / EPB, 256, 0, stream>>>(ei, bcur, pairs, flags);
    fine_fill<<<NBUCK, 512, 0, stream>>>(pairs, bbase, col_ptr, col_idx);

    // 4) pack weights + biases
    pack_all<<<515, 256, 0, stream>>>(W1, W2, Wp, b1, b2, bp,
                                      W1p, W2p, Wpp, b1b, b2b, bpb, flags);

    const int gemm_grid   = (NODES + 63) / 64;
    const int gather_grid = (NODES + 3) / 4;

    // 5) proj -> d_out (nt store), and emit Xs = dinv*x
    gemm_proj<<<gemm_grid, 256, 0, stream>>>(x, Wpp, dinv, bpb, d_out, Xs, flags);
    // 6) gather1: aggX = dinv*(sum Xs + self)
    gather1<<<gather_grid, 256, 0, stream>>>(col_ptr, col_idx, Xs, dinv, aggX);
    // 7) conv1 GEMM: H1 = relu(aggX@W1 + b1)
    gemm_tile<<<gemm_grid, 256, 0, stream>>>(aggX, W1p, FIN, nullptr, b1b, 1, H1);
    // 8) conv2 GEMM: Y2 = dinv*(H1@W2)   (Y2 overlays dead Xs+aggX)
    gemm_tile<<<gemm_grid, 256, 0, stream>>>(H1, W2p, FOUT, dinv, nullptr, 0, Y2);
    // 9) gather2: d_out = relu(dinv*(sum Y2 + self) + b2 + proj)
    gather2<<<gather_grid, 256, 0, stream>>>(col_ptr, col_idx, Y2, dinv, b2b,
                                             d_out, d_out, flags);
}